// Round 1
// baseline (322.556 us; speedup 1.0000x reference)
//
#include <hip/hip_runtime.h>

// DynamicConv2d: GAP->MLP->softmax routing, Wdyn = sum_k a_k * bank_k,
// then per-sample 3x3 conv (pad 1) = per-sample GEMM M=256,N=3136,K=1152.
// Strategy: bf16 MFMA implicit GEMM with NHWC padded input, k-contiguous Wdyn,
// global_load_lds(16B) staging, XOR-swizzled LDS to kill bank conflicts.

#define CIN    128
#define COUT   256
#define KEXP   8
#define HIDDEN 32
#define B_     32
#define H_     56
#define W_     56
#define HW     3136
#define HP     58      // 56 + 2 halo rows
#define WP     66      // 64 compute cols + 2 halo
#define KK     1152    // 9 * 128, order (kh*3+kw)*128 + cin

typedef float  v4f  __attribute__((ext_vector_type(4)));
typedef __bf16 v8bf __attribute__((ext_vector_type(8)));
// NOTE: if compile fails on the mfma builtin arg type, switch v8bf to
// "typedef short v8bf __attribute__((ext_vector_type(8)));" and bit-load.

__device__ __forceinline__ unsigned short f2bf(float x) {
  unsigned int u = __float_as_uint(x);
  u += 0x7fff + ((u >> 16) & 1);          // RNE
  return (unsigned short)(u >> 16);
}
__device__ __forceinline__ float bf2f(unsigned short s) {
  return __uint_as_float(((unsigned int)s) << 16);
}

// 16B-per-lane async global->LDS. LDS dest must be wave-uniform base; lane i
// lands at base + i*16. Global address is per-lane (free swizzling).
__device__ __forceinline__ void gl_lds16(const void* g, void* lds) {
  __builtin_amdgcn_global_load_lds(
      (__attribute__((address_space(1))) void*)(unsigned long long)(g),
      (__attribute__((address_space(3))) void*)(lds),
      16, 0, 0);
}

// ---------------------------------------------------------------------------
// Pass 1: x (NCHW f32) -> xp_t (padded NHWC bf16), fused GAP (atomicAdd to v).
// One block per (h, b). LDS tile[w][c] with XOR swizzle c^=(2w)&127 so both the
// w-strided writes and the c-contiguous reads are conflict-free.
// ---------------------------------------------------------------------------
__global__ __launch_bounds__(256) void k_xpose(const float* __restrict__ x,
                                               unsigned short* __restrict__ xpt,
                                               float* __restrict__ v) {
  const int h = blockIdx.x, b = blockIdx.y, tid = threadIdx.x;
  __shared__ unsigned short tile[56 * 128];
#pragma unroll
  for (int it = 0; it < 28; ++it) {           // 28*256 = 7168 = 128c * 56w
    int idx = it * 256 + tid;
    int c = idx / 56;
    int w = idx - c * 56;
    float val = x[((b * CIN + c) * H_ + h) * W_ + w];
    tile[w * 128 + (c ^ ((2 * w) & 127))] = f2bf(val);
  }
  __syncthreads();
  if (tid < 128) {                            // GAP partial for this row
    float s = 0.f;
    for (int w = 0; w < 56; ++w) s += bf2f(tile[w * 128 + (tid ^ ((2 * w) & 127))]);
    atomicAdd(v + b * CIN + tid, s * (1.0f / 3136.0f));
  }
#pragma unroll
  for (int it = 0; it < 28; ++it) {           // write NHWC rows, 256B contiguous
    int idx = it * 256 + tid;
    int w = idx >> 7, c = idx & 127;
    xpt[((size_t)(b * HP + (h + 1)) * WP + (w + 1)) * CIN + c] =
        tile[w * 128 + (c ^ ((2 * w) & 127))];
  }
}

// ---------------------------------------------------------------------------
// Pass 2: MLP + softmax routing. v already holds the mean. grid=32, block=64.
// ---------------------------------------------------------------------------
__global__ void k_mlp(const float* __restrict__ v, const float* __restrict__ fc1w,
                      const float* __restrict__ fc1b, const float* __restrict__ fc2w,
                      const float* __restrict__ fc2b, float* __restrict__ aout) {
  const int b = blockIdx.x, t = threadIdx.x;
  __shared__ float hid[HIDDEN];
  __shared__ float lg[KEXP];
  if (t < HIDDEN) {
    float s = fc1b[t];
    const float* vb = v + b * CIN;
    const float* wr = fc1w + t * CIN;
    for (int c = 0; c < CIN; ++c) s += vb[c] * wr[c];
    hid[t] = fmaxf(s, 0.f);
  }
  __syncthreads();
  if (t < KEXP) {
    float s = fc2b[t];
    const float* wr = fc2w + t * HIDDEN;
    for (int j = 0; j < HIDDEN; ++j) s += hid[j] * wr[j];
    lg[t] = s;
  }
  __syncthreads();
  if (t == 0) {
    float m = lg[0];
    for (int k = 1; k < KEXP; ++k) m = fmaxf(m, lg[k]);
    float e[KEXP], den = 0.f;
    for (int k = 0; k < KEXP; ++k) { e[k] = expf(lg[k] - m); den += e[k]; }
    float inv = 1.0f / den;
    for (int k = 0; k < KEXP; ++k) aout[b * KEXP + k] = e[k] * inv;
  }
}

// ---------------------------------------------------------------------------
// Pass 3: Wdyn[b][cout][kk] bf16, kk = (kh*3+kw)*128 + cin (k-contiguous for
// the GEMM A operand). bank layout is [k][cout][cin][kh][kw] -> stride-9 gather
// (L2-served after first sample). 4 outputs/thread, ushort4 store.
// ---------------------------------------------------------------------------
__global__ __launch_bounds__(256) void k_wdyn(const float* __restrict__ aout,
                                              const float* __restrict__ bank,
                                              unsigned short* __restrict__ wdyn) {
  int o4 = (blockIdx.x * 256 + threadIdx.x) * 4;   // 9216 blocks * 1024 = 9437184
  int b = o4 / (COUT * KK);
  int r = o4 - b * (COUT * KK);
  int cout = r / KK;
  int kk = r - cout * KK;
  int khw = kk >> 7;
  int cin = kk & 127;
  float av[KEXP];
#pragma unroll
  for (int k = 0; k < KEXP; ++k) av[k] = aout[b * KEXP + k];
  float r0 = 0.f, r1 = 0.f, r2 = 0.f, r3 = 0.f;
#pragma unroll
  for (int k = 0; k < KEXP; ++k) {
    const float* bp = bank + (size_t)((k * COUT + cout) * CIN + cin) * 9 + khw;
    r0 += av[k] * bp[0];
    r1 += av[k] * bp[9];
    r2 += av[k] * bp[18];
    r3 += av[k] * bp[27];
  }
  ushort4 o;
  o.x = f2bf(r0); o.y = f2bf(r1); o.z = f2bf(r2); o.w = f2bf(r3);
  *(ushort4*)(wdyn + o4) = o;
}

// ---------------------------------------------------------------------------
// Pass 4: the conv as MFMA GEMM. Block: 128 couts x 128 pixels (2 image rows
// padded to 64 cols). K-loop: 18 tiles of BK=64 (fixed (kh,kw), 64 cins).
// Staging: global_load_lds 16B chunks; LDS chunk index = row*8 + (c ^ (row&7))
// so wave64 ds_read_b128 frag reads are bank-conflict-free.
// Frag maps (HW-verified): A: m=lane&15, k=8*(lane>>4)+j ; C/D: col=lane&15,
// row=4*(lane>>4)+reg.
// ---------------------------------------------------------------------------
__global__ __launch_bounds__(256) void k_conv(const unsigned short* __restrict__ wdyn,
                                              const unsigned short* __restrict__ xpt,
                                              float* __restrict__ out) {
  const int bx = blockIdx.x;          // 56 = 2 m-tiles * 28 row-pairs
  const int b  = blockIdx.y;          // 32 samples
  const int bm = bx & 1, rp = bx >> 1;
  const int h0 = rp * 2;
  const int tid = threadIdx.x;
  const int wv = tid >> 6, l = tid & 63;
  const int q = l >> 4, l15 = l & 15;
  const int mq = (wv & 1) * 64, nq = (wv >> 1) * 64;

  __shared__ __align__(16) unsigned short Ash[128 * 64];  // [cout][k] swizzled
  __shared__ __align__(16) unsigned short Bsh[128 * 64];  // [pixel][k] swizzled

  const unsigned short* wb = wdyn + (size_t)(b * COUT + bm * 128) * KK;
  const unsigned short* xb = xpt + (size_t)b * HP * WP * CIN;

  v4f acc[4][4];
#pragma unroll
  for (int i = 0; i < 4; ++i)
#pragma unroll
    for (int j = 0; j < 4; ++j)
#pragma unroll
      for (int rr = 0; rr < 4; ++rr) acc[i][j][rr] = 0.f;

  for (int t = 0; t < 18; ++t) {
    const int khw = t >> 1, cinb = (t & 1) << 6;
    const int kh = khw / 3, kw = khw - 3 * kh;
    // A stage: 1024 chunks of 16B
#pragma unroll
    for (int it = 0; it < 4; ++it) {
      int g = it * 256 + tid;
      int row = g >> 3;
      int c = (g & 7) ^ (row & 7);               // logical chunk for this slot
      gl_lds16(wb + (size_t)row * KK + t * 64 + c * 8,
               Ash + (it * 256 + wv * 64) * 8);
    }
    // B stage: 1024 chunks; row p -> (out row p>>6, col p&63)
#pragma unroll
    for (int it = 0; it < 4; ++it) {
      int g = it * 256 + tid;
      int p = g >> 3;
      int c = (g & 7) ^ (p & 7);
      int hh = h0 + (p >> 6) + kh;               // <= 57 < HP
      int ww = (p & 63) + kw;                    // <= 65 < WP
      gl_lds16(xb + (size_t)(hh * WP + ww) * CIN + cinb + c * 8,
               Bsh + (it * 256 + wv * 64) * 8);
    }
    __syncthreads();   // compiler emits vmcnt(0) drain for the LDS-DMA here
#pragma unroll
    for (int ks = 0; ks < 2; ++ks) {
      v8bf af[4], bfr[4];
#pragma unroll
      for (int i = 0; i < 4; ++i) {
        int row = mq + 16 * i + l15;
        int phys = (q + 4 * ks) ^ (row & 7);
        af[i] = *(const v8bf*)(Ash + (row * 8 + phys) * 8);
      }
#pragma unroll
      for (int j = 0; j < 4; ++j) {
        int p = nq + 16 * j + l15;
        int phys = (q + 4 * ks) ^ (p & 7);
        bfr[j] = *(const v8bf*)(Bsh + (p * 8 + phys) * 8);
      }
#pragma unroll
      for (int i = 0; i < 4; ++i)
#pragma unroll
        for (int j = 0; j < 4; ++j)
          acc[i][j] = __builtin_amdgcn_mfma_f32_16x16x32_bf16(af[i], bfr[j],
                                                              acc[i][j], 0, 0, 0);
    }
    __syncthreads();
  }

  // Epilogue: D col = pixel (lane&15), D rows = cout base + 4q + r
#pragma unroll
  for (int j = 0; j < 4; ++j) {
    int p = nq + 16 * j + l15;
    int w = p & 63, hr = h0 + (p >> 6);
    if (w < 56) {
#pragma unroll
      for (int i = 0; i < 4; ++i) {
        int cout = bm * 128 + mq + 16 * i + 4 * q;
        float* op = out + ((size_t)(b * COUT + cout) * H_ + hr) * W_ + w;
#pragma unroll
        for (int rr = 0; rr < 4; ++rr) op[(size_t)rr * HW] = acc[i][j][rr];
      }
    }
  }
}

// ---------------------------------------------------------------------------
// Workspace layout (requires ~48 MB):
//   [0,16384)                     v    (32*128 f32, zeroed, atomics target)
//   [16384,17408)                 a    (32*8 f32)
//   [17408, +18874368)            Wdyn bf16 [b][cout][1152]
//   [18891776, +31358976)         xp_t bf16 [b][58][66][128] (zeroed borders)
// ---------------------------------------------------------------------------
extern "C" void kernel_launch(void* const* d_in, const int* in_sizes, int n_in,
                              void* d_out, int out_size, void* d_ws, size_t ws_size,
                              hipStream_t stream) {
  const float* x    = (const float*)d_in[0];
  const float* bank = (const float*)d_in[1];
  const float* fc1w = (const float*)d_in[2];
  const float* fc1b = (const float*)d_in[3];
  const float* fc2w = (const float*)d_in[4];
  const float* fc2b = (const float*)d_in[5];
  float* out = (float*)d_out;

  char* ws = (char*)d_ws;
  float* v    = (float*)(ws + 0);
  float* aout = (float*)(ws + 16384);
  unsigned short* wdyn = (unsigned short*)(ws + 17408);
  unsigned short* xpt  = (unsigned short*)(ws + 17408 + 18874368);

  hipMemsetAsync(v, 0, 16384, stream);
  hipMemsetAsync(xpt, 0, (size_t)B_ * HP * WP * CIN * 2, stream);

  k_xpose<<<dim3(H_, B_), 256, 0, stream>>>(x, xpt, v);
  k_mlp<<<dim3(B_), 64, 0, stream>>>(v, fc1w, fc1b, fc2w, fc2b, aout);
  k_wdyn<<<dim3(9216), 256, 0, stream>>>(aout, bank, wdyn);
  k_conv<<<dim3(56, B_), 256, 0, stream>>>(wdyn, xpt, out);
}

// Round 3
// 264.123 us; speedup vs baseline: 1.2212x; 1.2212x over previous
//
#include <hip/hip_runtime.h>

// DynamicConv2d: GAP->MLP->softmax routing, Wdyn = sum_k a_k * bank_k,
// then per-sample 3x3 conv (pad 1) = per-sample GEMM M=256,N=3136,K=1152.
// R3: fix k_xpose store-loop trip count (1792 ushort4 stores, was 896 ->
// half of every row left zero). k_conv byte-identical to R1/R2.

#define CIN    128
#define COUT   256
#define KEXP   8
#define HIDDEN 32
#define B_     32
#define H_     56
#define W_     56
#define HW     3136
#define HP     58      // 56 + 2 halo rows
#define WP     66      // 64 compute cols + 2 halo
#define KK     1152    // 9 * 128, order (kh*3+kw)*128 + cin

typedef float  v4f  __attribute__((ext_vector_type(4)));
typedef __bf16 v8bf __attribute__((ext_vector_type(8)));

__device__ __forceinline__ unsigned short f2bf(float x) {
  unsigned int u = __float_as_uint(x);
  u += 0x7fff + ((u >> 16) & 1);          // RNE
  return (unsigned short)(u >> 16);
}
__device__ __forceinline__ float bf2f(unsigned short s) {
  return __uint_as_float(((unsigned int)s) << 16);
}

// 16B-per-lane async global->LDS. LDS dest is wave-uniform base + lane*16.
__device__ __forceinline__ void gl_lds16(const void* g, void* lds) {
  __builtin_amdgcn_global_load_lds(
      (__attribute__((address_space(1))) void*)(unsigned long long)(g),
      (__attribute__((address_space(3))) void*)(lds),
      16, 0, 0);
}

// ---------------------------------------------------------------------------
// Pass 1 (v3): x (NCHW f32) -> xp_t (padded NHWC bf16) + fused GAP.
// One block per (h, b). float4 global loads; f32 LDS tile padded to 129;
// GAP uses all 256 threads; 1792 ushort4 NHWC stores (7 full iterations).
// ---------------------------------------------------------------------------
__global__ __launch_bounds__(256) void k_xpose(const float* __restrict__ x,
                                               unsigned short* __restrict__ xpt,
                                               float* __restrict__ v) {
  const int h = blockIdx.x, b = blockIdx.y, tid = threadIdx.x;
  __shared__ float tf[56 * 129];      // 28.9 KB
  __shared__ float gp[256];
  const float4* xr4 = (const float4*)x + (size_t)b * CIN * 784;  // 784=3136/4

#pragma unroll
  for (int it = 0; it < 7; ++it) {    // 1792 float4 = 128c * 14wq
    int idx = it * 256 + tid;
    int c  = idx / 14;
    int wq = idx - c * 14;
    float4 q = xr4[(size_t)c * 784 + h * 14 + wq];
    int w0 = wq * 4;
    tf[(w0 + 0) * 129 + c] = q.x;
    tf[(w0 + 1) * 129 + c] = q.y;
    tf[(w0 + 2) * 129 + c] = q.z;
    tf[(w0 + 3) * 129 + c] = q.w;
  }
  __syncthreads();

  {                                   // GAP partial: 256 threads, 28 reads each
    int c = tid & 127, half = tid >> 7;
    float s = 0.f;
#pragma unroll
    for (int w = half * 28; w < half * 28 + 28; ++w) s += tf[w * 129 + c];
    gp[tid] = s;
  }

#pragma unroll
  for (int it = 0; it < 7; ++it) {    // 1792 ushort4 stores = 56w * 32 c-quads
    int idx = it * 256 + tid;
    int w  = idx >> 5;                // [0,56)
    int c4 = (idx & 31) << 2;         // [0,128) step 4
    ushort4 o;
    o.x = f2bf(tf[w * 129 + c4 + 0]);
    o.y = f2bf(tf[w * 129 + c4 + 1]);
    o.z = f2bf(tf[w * 129 + c4 + 2]);
    o.w = f2bf(tf[w * 129 + c4 + 3]);
    *(ushort4*)(xpt + ((size_t)(b * HP + (h + 1)) * WP + (w + 1)) * CIN + c4) = o;
  }
  __syncthreads();
  if (tid < 128)
    atomicAdd(v + b * CIN + tid, (gp[tid] + gp[tid + 128]) * (1.0f / 3136.0f));
}

// ---------------------------------------------------------------------------
// Pass 2: MLP + softmax routing (unchanged). grid=32, block=64.
// ---------------------------------------------------------------------------
__global__ void k_mlp(const float* __restrict__ v, const float* __restrict__ fc1w,
                      const float* __restrict__ fc1b, const float* __restrict__ fc2w,
                      const float* __restrict__ fc2b, float* __restrict__ aout) {
  const int b = blockIdx.x, t = threadIdx.x;
  __shared__ float hid[HIDDEN];
  __shared__ float lg[KEXP];
  if (t < HIDDEN) {
    float s = fc1b[t];
    const float* vb = v + b * CIN;
    const float* wr = fc1w + t * CIN;
    for (int c = 0; c < CIN; ++c) s += vb[c] * wr[c];
    hid[t] = fmaxf(s, 0.f);
  }
  __syncthreads();
  if (t < KEXP) {
    float s = fc2b[t];
    const float* wr = fc2w + t * HIDDEN;
    for (int j = 0; j < HIDDEN; ++j) s += hid[j] * wr[j];
    lg[t] = s;
  }
  __syncthreads();
  if (t == 0) {
    float m = lg[0];
    for (int k = 1; k < KEXP; ++k) m = fmaxf(m, lg[k]);
    float e[KEXP], den = 0.f;
    for (int k = 0; k < KEXP; ++k) { e[k] = expf(lg[k] - m); den += e[k]; }
    float inv = 1.0f / den;
    for (int k = 0; k < KEXP; ++k) aout[b * KEXP + k] = e[k] * inv;
  }
}

// ---------------------------------------------------------------------------
// Pass 3 (v2): Wdyn[b][cout][kk] bf16, kk = khw*128 + cin.
// One block per cout. Stage 8 expert rows (1152 f32 each) in LDS via float4;
// thread owns 8 samples x 64-lane kk slice, coeffs in VGPRs; stride-9 LDS
// reads = 2/bank = free; coalesced bf16 stores.
// ---------------------------------------------------------------------------
__global__ __launch_bounds__(256) void k_wdyn(const float* __restrict__ aout,
                                              const float* __restrict__ bank,
                                              unsigned short* __restrict__ wdyn) {
  const int cout = blockIdx.x, tid = threadIdx.x;
  __shared__ float4 bS4[KEXP * 288];          // 8 experts * 1152 floats = 36 KB
  __shared__ float aS[B_ * KEXP];             // 256 routing coeffs

#pragma unroll
  for (int k = 0; k < KEXP; ++k) {
    const float4* bp = (const float4*)(bank + (size_t)(k * COUT + cout) * KK);
    for (int it = tid; it < 288; it += 256) bS4[k * 288 + it] = bp[it];
  }
  aS[tid] = aout[tid];
  __syncthreads();

  const float* bS = (const float*)bS4;
  const int lane_kk = tid & 63;
  const int bg = tid >> 6;                    // 4 groups of 8 samples
  float areg[8][KEXP];
#pragma unroll
  for (int bi = 0; bi < 8; ++bi)
#pragma unroll
    for (int k = 0; k < KEXP; ++k) areg[bi][k] = aS[(bg * 8 + bi) * KEXP + k];

  for (int it = 0; it < 18; ++it) {
    int kk  = it * 64 + lane_kk;              // [0,1152)
    int khw = kk >> 7, cin = kk & 127;
    int e   = cin * 9 + khw;
    float vv[KEXP];
#pragma unroll
    for (int k = 0; k < KEXP; ++k) vv[k] = bS[k * KK + e];
#pragma unroll
    for (int bi = 0; bi < 8; ++bi) {
      float s = 0.f;
#pragma unroll
      for (int k = 0; k < KEXP; ++k) s += areg[bi][k] * vv[k];
      wdyn[(size_t)((bg * 8 + bi) * COUT + cout) * KK + kk] = f2bf(s);
    }
  }
}

// ---------------------------------------------------------------------------
// Pass 4: the conv as MFMA GEMM (byte-identical to R1/R2).
// ---------------------------------------------------------------------------
__global__ __launch_bounds__(256) void k_conv(const unsigned short* __restrict__ wdyn,
                                              const unsigned short* __restrict__ xpt,
                                              float* __restrict__ out) {
  const int bx = blockIdx.x;          // 56 = 2 m-tiles * 28 row-pairs
  const int b  = blockIdx.y;          // 32 samples
  const int bm = bx & 1, rp = bx >> 1;
  const int h0 = rp * 2;
  const int tid = threadIdx.x;
  const int wv = tid >> 6, l = tid & 63;
  const int q = l >> 4, l15 = l & 15;
  const int mq = (wv & 1) * 64, nq = (wv >> 1) * 64;

  __shared__ __align__(16) unsigned short Ash[128 * 64];  // [cout][k] swizzled
  __shared__ __align__(16) unsigned short Bsh[128 * 64];  // [pixel][k] swizzled

  const unsigned short* wb = wdyn + (size_t)(b * COUT + bm * 128) * KK;
  const unsigned short* xb = xpt + (size_t)b * HP * WP * CIN;

  v4f acc[4][4];
#pragma unroll
  for (int i = 0; i < 4; ++i)
#pragma unroll
    for (int j = 0; j < 4; ++j)
#pragma unroll
      for (int rr = 0; rr < 4; ++rr) acc[i][j][rr] = 0.f;

  for (int t = 0; t < 18; ++t) {
    const int khw = t >> 1, cinb = (t & 1) << 6;
    const int kh = khw / 3, kw = khw - 3 * kh;
#pragma unroll
    for (int it = 0; it < 4; ++it) {
      int g = it * 256 + tid;
      int row = g >> 3;
      int c = (g & 7) ^ (row & 7);
      gl_lds16(wb + (size_t)row * KK + t * 64 + c * 8,
               Ash + (it * 256 + wv * 64) * 8);
    }
#pragma unroll
    for (int it = 0; it < 4; ++it) {
      int g = it * 256 + tid;
      int p = g >> 3;
      int c = (g & 7) ^ (p & 7);
      int hh = h0 + (p >> 6) + kh;
      int ww = (p & 63) + kw;
      gl_lds16(xb + (size_t)(hh * WP + ww) * CIN + cinb + c * 8,
               Bsh + (it * 256 + wv * 64) * 8);
    }
    __syncthreads();
#pragma unroll
    for (int ks = 0; ks < 2; ++ks) {
      v8bf af[4], bfr[4];
#pragma unroll
      for (int i = 0; i < 4; ++i) {
        int row = mq + 16 * i + l15;
        int phys = (q + 4 * ks) ^ (row & 7);
        af[i] = *(const v8bf*)(Ash + (row * 8 + phys) * 8);
      }
#pragma unroll
      for (int j = 0; j < 4; ++j) {
        int p = nq + 16 * j + l15;
        int phys = (q + 4 * ks) ^ (p & 7);
        bfr[j] = *(const v8bf*)(Bsh + (p * 8 + phys) * 8);
      }
#pragma unroll
      for (int i = 0; i < 4; ++i)
#pragma unroll
        for (int j = 0; j < 4; ++j)
          acc[i][j] = __builtin_amdgcn_mfma_f32_16x16x32_bf16(af[i], bfr[j],
                                                              acc[i][j], 0, 0, 0);
    }
    __syncthreads();
  }

#pragma unroll
  for (int j = 0; j < 4; ++j) {
    int p = nq + 16 * j + l15;
    int w = p & 63, hr = h0 + (p >> 6);
    if (w < 56) {
#pragma unroll
      for (int i = 0; i < 4; ++i) {
        int cout = bm * 128 + mq + 16 * i + 4 * q;
        float* op = out + ((size_t)(b * COUT + cout) * H_ + hr) * W_ + w;
#pragma unroll
        for (int rr = 0; rr < 4; ++rr) op[(size_t)rr * HW] = acc[i][j][rr];
      }
    }
  }
}

// ---------------------------------------------------------------------------
// Workspace layout (~48 MB):
//   [0,16384)                     v    (32*128 f32, zeroed, atomics target)
//   [16384,17408)                 a    (32*8 f32)
//   [17408, +18874368)            Wdyn bf16 [b][cout][1152]
//   [18891776, +31358976)         xp_t bf16 [b][58][66][128] (zeroed borders)
// ---------------------------------------------------------------------------
extern "C" void kernel_launch(void* const* d_in, const int* in_sizes, int n_in,
                              void* d_out, int out_size, void* d_ws, size_t ws_size,
                              hipStream_t stream) {
  const float* x    = (const float*)d_in[0];
  const float* bank = (const float*)d_in[1];
  const float* fc1w = (const float*)d_in[2];
  const float* fc1b = (const float*)d_in[3];
  const float* fc2w = (const float*)d_in[4];
  const float* fc2b = (const float*)d_in[5];
  float* out = (float*)d_out;

  char* ws = (char*)d_ws;
  float* v    = (float*)(ws + 0);
  float* aout = (float*)(ws + 16384);
  unsigned short* wdyn = (unsigned short*)(ws + 17408);
  unsigned short* xpt  = (unsigned short*)(ws + 17408 + 18874368);

  hipMemsetAsync(v, 0, 16384, stream);
  hipMemsetAsync(xpt, 0, (size_t)B_ * HP * WP * CIN * 2, stream);

  k_xpose<<<dim3(H_, B_), 256, 0, stream>>>(x, xpt, v);
  k_mlp<<<dim3(B_), 64, 0, stream>>>(v, fc1w, fc1b, fc2w, fc2b, aout);
  k_wdyn<<<dim3(COUT), 256, 0, stream>>>(aout, bank, wdyn);
  k_conv<<<dim3(56, B_), 256, 0, stream>>>(wdyn, xpt, out);
}

// Round 4
// 249.996 us; speedup vs baseline: 1.2902x; 1.0565x over previous
//
#include <hip/hip_runtime.h>

// DynamicConv2d: GAP->MLP->softmax routing, Wdyn = sum_k a_k * bank_k,
// then per-sample 3x3 conv (pad 1) = per-sample GEMM M=256,N=3136,K=1152.
// R4: (1) no memsets, no atomics - xpose zeroes halos + writes gpart, mlp
// reduces; (2) conv uses exact flattened-pixel tiling (WP=58, 25 chunks of
// 128 pixels, 2% waste vs 12.5%); (3) wdyn at 512 threads. 4 dispatches.

#define CIN    128
#define COUT   256
#define KEXP   8
#define HIDDEN 32
#define B_     32
#define H_     56
#define W_     56
#define HW     3136
#define HP     58      // 1 + 56 + 1 halo rows
#define WP     58      // 1 + 56 + 1 halo cols
#define KK     1152    // 9 * 128, order (kh*3+kw)*128 + cin

typedef float  v4f  __attribute__((ext_vector_type(4)));
typedef __bf16 v8bf __attribute__((ext_vector_type(8)));

__device__ __forceinline__ unsigned short f2bf(float x) {
  unsigned int u = __float_as_uint(x);
  u += 0x7fff + ((u >> 16) & 1);          // RNE
  return (unsigned short)(u >> 16);
}

// 16B-per-lane async global->LDS. LDS dest is wave-uniform base + lane*16.
__device__ __forceinline__ void gl_lds16(const void* g, void* lds) {
  __builtin_amdgcn_global_load_lds(
      (__attribute__((address_space(1))) void*)(unsigned long long)(g),
      (__attribute__((address_space(3))) void*)(lds),
      16, 0, 0);
}

// ---------------------------------------------------------------------------
// Pass 1 (v4): x (NCHW f32) -> xp_t (padded NHWC bf16, WP=58) + GAP partials
// to gpart[h][b][c] (no atomics). Blocks also zero their own halo cells:
// cols 0/57 each row; rows 0/57 by the h==0 / h==55 blocks.
// ---------------------------------------------------------------------------
__global__ __launch_bounds__(256) void k_xpose(const float* __restrict__ x,
                                               unsigned short* __restrict__ xpt,
                                               float* __restrict__ gpart) {
  const int h = blockIdx.x, b = blockIdx.y, tid = threadIdx.x;
  __shared__ float tf[56 * 129];      // 28.9 KB
  __shared__ float gp[256];
  const float4* xr4 = (const float4*)x + (size_t)b * CIN * 784;  // 784=3136/4

#pragma unroll
  for (int it = 0; it < 7; ++it) {    // 1792 float4 = 128c * 14wq
    int idx = it * 256 + tid;
    int c  = idx / 14;
    int wq = idx - c * 14;
    float4 q = xr4[(size_t)c * 784 + h * 14 + wq];
    int w0 = wq * 4;
    tf[(w0 + 0) * 129 + c] = q.x;
    tf[(w0 + 1) * 129 + c] = q.y;
    tf[(w0 + 2) * 129 + c] = q.z;
    tf[(w0 + 3) * 129 + c] = q.w;
  }
  __syncthreads();

  {                                   // GAP partial: 256 threads, 28 reads each
    int c = tid & 127, half = tid >> 7;
    float s = 0.f;
#pragma unroll
    for (int w = half * 28; w < half * 28 + 28; ++w) s += tf[w * 129 + c];
    gp[tid] = s;
  }

#pragma unroll
  for (int it = 0; it < 7; ++it) {    // 1792 ushort4 stores = 56w * 32 c-quads
    int idx = it * 256 + tid;
    int w  = idx >> 5;                // [0,56)
    int c4 = (idx & 31) << 2;         // [0,128) step 4
    ushort4 o;
    o.x = f2bf(tf[w * 129 + c4 + 0]);
    o.y = f2bf(tf[w * 129 + c4 + 1]);
    o.z = f2bf(tf[w * 129 + c4 + 2]);
    o.w = f2bf(tf[w * 129 + c4 + 3]);
    *(ushort4*)(xpt + ((size_t)(b * HP + (h + 1)) * WP + (w + 1)) * CIN + c4) = o;
  }

  // halo columns 0 and 57 of this image row
  if (tid < 128) {
    size_t rb = (size_t)(b * HP + (h + 1)) * WP * CIN;
    xpt[rb + tid] = 0;
    xpt[rb + 57 * CIN + tid] = 0;
  }
  // halo rows 0 and 57 (full 58*128 ushorts each)
  if (h == 0 || h == 55) {
    int hr = (h == 0) ? 0 : 57;
    size_t rb = (size_t)(b * HP + hr) * WP * CIN;
    ushort4 z; z.x = z.y = z.z = z.w = 0;
    for (int i = tid; i < 1856; i += 256)
      *(ushort4*)(xpt + rb + i * 4) = z;
  }

  __syncthreads();
  if (tid < 128)
    gpart[((size_t)h * B_ + b) * CIN + tid] =
        (gp[tid] + gp[tid + 128]) * (1.0f / 3136.0f);
}

// ---------------------------------------------------------------------------
// Pass 2 (v2): reduce gpart -> v (in LDS), then MLP + softmax. grid=32,
// block=128. gpart reads are lane-coalesced (128 consecutive floats).
// ---------------------------------------------------------------------------
__global__ void k_mlp(const float* __restrict__ gpart, const float* __restrict__ fc1w,
                      const float* __restrict__ fc1b, const float* __restrict__ fc2w,
                      const float* __restrict__ fc2b, float* __restrict__ aout) {
  const int b = blockIdx.x, t = threadIdx.x;
  __shared__ float vS[CIN];
  __shared__ float hid[HIDDEN];
  __shared__ float lg[KEXP];
  {
    float s = 0.f;
    for (int h = 0; h < H_; ++h) s += gpart[((size_t)h * B_ + b) * CIN + t];
    vS[t] = s;
  }
  __syncthreads();
  if (t < HIDDEN) {
    float s = fc1b[t];
    const float* wr = fc1w + t * CIN;
    for (int c = 0; c < CIN; ++c) s += vS[c] * wr[c];
    hid[t] = fmaxf(s, 0.f);
  }
  __syncthreads();
  if (t < KEXP) {
    float s = fc2b[t];
    const float* wr = fc2w + t * HIDDEN;
    for (int j = 0; j < HIDDEN; ++j) s += hid[j] * wr[j];
    lg[t] = s;
  }
  __syncthreads();
  if (t == 0) {
    float m = lg[0];
    for (int k = 1; k < KEXP; ++k) m = fmaxf(m, lg[k]);
    float e[KEXP], den = 0.f;
    for (int k = 0; k < KEXP; ++k) { e[k] = expf(lg[k] - m); den += e[k]; }
    float inv = 1.0f / den;
    for (int k = 0; k < KEXP; ++k) aout[b * KEXP + k] = e[k] * inv;
  }
}

// ---------------------------------------------------------------------------
// Pass 3 (v3): Wdyn[b][cout][kk] bf16, kk = khw*128 + cin. One block of 512
// threads per cout (8 waves/CU). Stage 8 expert rows (1152 f32) via float4;
// thread = (lane_kk 64) x (sg 8), owns 4 samples; stride-9 LDS reads are
// 2/bank = free; coalesced bf16 stores.
// ---------------------------------------------------------------------------
__global__ __launch_bounds__(512) void k_wdyn(const float* __restrict__ aout,
                                              const float* __restrict__ bank,
                                              unsigned short* __restrict__ wdyn) {
  const int cout = blockIdx.x, tid = threadIdx.x;
  __shared__ float4 bS4[KEXP * 288];          // 36 KB
  __shared__ float aS[B_ * KEXP];             // 256 routing coeffs

  for (int idx = tid; idx < KEXP * 288; idx += 512) {
    int k = idx / 288, r = idx - k * 288;
    bS4[idx] = ((const float4*)(bank + (size_t)(k * COUT + cout) * KK))[r];
  }
  if (tid < 256) aS[tid] = aout[tid];
  __syncthreads();

  const float* bS = (const float*)bS4;
  const int lane_kk = tid & 63;
  const int sg = tid >> 6;                    // 8 groups of 4 samples
  float areg[4][KEXP];
#pragma unroll
  for (int bi = 0; bi < 4; ++bi)
#pragma unroll
    for (int k = 0; k < KEXP; ++k) areg[bi][k] = aS[(sg * 4 + bi) * KEXP + k];

  for (int it = 0; it < 18; ++it) {
    int kk  = it * 64 + lane_kk;              // [0,1152)
    int khw = kk >> 7, cin = kk & 127;
    int e   = cin * 9 + khw;
    float vv[KEXP];
#pragma unroll
    for (int k = 0; k < KEXP; ++k) vv[k] = bS[k * KK + e];
#pragma unroll
    for (int bi = 0; bi < 4; ++bi) {
      float s = 0.f;
#pragma unroll
      for (int k = 0; k < KEXP; ++k) s += areg[bi][k] * vv[k];
      wdyn[(size_t)((sg * 4 + bi) * COUT + cout) * KK + kk] = f2bf(s);
    }
  }
}

// ---------------------------------------------------------------------------
// Pass 4 (v2): conv as MFMA GEMM with exact flattened-pixel tiling.
// Block: 128 couts (bm) x 128 pixels (chunk of flat p). 25 chunks: 24 full +
// 1 half (clamped reads, masked stores). B address: row = p/56 + kh,
// col = p%56 + kw in the 58x58 halo image. Same verified swizzle/MFMA body.
// ---------------------------------------------------------------------------
__global__ __launch_bounds__(256) void k_conv(const unsigned short* __restrict__ wdyn,
                                              const unsigned short* __restrict__ xpt,
                                              float* __restrict__ out) {
  const int bx = blockIdx.x;          // 50 = 2 m-tiles * 25 pixel chunks
  const int b  = blockIdx.y;          // 32 samples
  const int bm = bx & 1, ch = bx >> 1;
  const int p0 = ch * 128;
  const int tid = threadIdx.x;
  const int wv = tid >> 6, l = tid & 63;
  const int q = l >> 4, l15 = l & 15;
  const int mq = (wv & 1) * 64, nq = (wv >> 1) * 64;

  __shared__ __align__(16) unsigned short Ash[128 * 64];  // [cout][k] swizzled
  __shared__ __align__(16) unsigned short Bsh[128 * 64];  // [pixel][k] swizzled

  const unsigned short* wb = wdyn + (size_t)(b * COUT + bm * 128) * KK;
  const unsigned short* xb = xpt + (size_t)b * HP * WP * CIN;

  v4f acc[4][4];
#pragma unroll
  for (int i = 0; i < 4; ++i)
#pragma unroll
    for (int j = 0; j < 4; ++j)
#pragma unroll
      for (int rr = 0; rr < 4; ++rr) acc[i][j][rr] = 0.f;

  for (int t = 0; t < 18; ++t) {
    const int khw = t >> 1, cinb = (t & 1) << 6;
    const int kh = khw / 3, kw = khw - 3 * kh;
#pragma unroll
    for (int it = 0; it < 4; ++it) {
      int g = it * 256 + tid;
      int row = g >> 3;
      int c = (g & 7) ^ (row & 7);
      gl_lds16(wb + (size_t)row * KK + t * 64 + c * 8,
               Ash + (it * 256 + wv * 64) * 8);
    }
#pragma unroll
    for (int it = 0; it < 4; ++it) {
      int g = it * 256 + tid;
      int prow = g >> 3;
      int c = (g & 7) ^ (prow & 7);
      int p = p0 + prow;
      p = p > 3135 ? 3135 : p;                 // clamp (half chunk 24)
      int ph = p / 56;
      int pw = p - ph * 56;
      gl_lds16(xb + (size_t)((ph + kh) * WP + pw + kw) * CIN + cinb + c * 8,
               Bsh + (it * 256 + wv * 64) * 8);
    }
    __syncthreads();
#pragma unroll
    for (int ks = 0; ks < 2; ++ks) {
      v8bf af[4], bfr[4];
#pragma unroll
      for (int i = 0; i < 4; ++i) {
        int row = mq + 16 * i + l15;
        int phys = (q + 4 * ks) ^ (row & 7);
        af[i] = *(const v8bf*)(Ash + (row * 8 + phys) * 8);
      }
#pragma unroll
      for (int j = 0; j < 4; ++j) {
        int p = nq + 16 * j + l15;
        int phys = (q + 4 * ks) ^ (p & 7);
        bfr[j] = *(const v8bf*)(Bsh + (p * 8 + phys) * 8);
      }
#pragma unroll
      for (int i = 0; i < 4; ++i)
#pragma unroll
        for (int j = 0; j < 4; ++j)
          acc[i][j] = __builtin_amdgcn_mfma_f32_16x16x32_bf16(af[i], bfr[j],
                                                              acc[i][j], 0, 0, 0);
    }
    __syncthreads();
  }

  // Epilogue: D col = pixel (lane&15), D rows = cout base + 4q + rr.
  // out flat index = (b*COUT + cout)*3136 + p (contiguous in p).
#pragma unroll
  for (int j = 0; j < 4; ++j) {
    int p = p0 + nq + 16 * j + l15;
    if (p < HW) {
#pragma unroll
      for (int i = 0; i < 4; ++i) {
        int cout = bm * 128 + mq + 16 * i + 4 * q;
        float* op = out + (size_t)(b * COUT + cout) * HW + p;
#pragma unroll
        for (int rr = 0; rr < 4; ++rr) op[(size_t)rr * HW] = acc[i][j][rr];
      }
    }
  }
}

// ---------------------------------------------------------------------------
// Workspace layout (~48.5 MB, all regions fully written before read):
//   [0, 917504)            gpart f32 [56][32][128]
//   [1 MB, +1024)          a f32 [32][8]
//   [2 MB, +18874368)      Wdyn bf16 [b][cout][1152]
//   [2MB+18874368, +27553792)  xp_t bf16 [b][58][58][128]
// ---------------------------------------------------------------------------
extern "C" void kernel_launch(void* const* d_in, const int* in_sizes, int n_in,
                              void* d_out, int out_size, void* d_ws, size_t ws_size,
                              hipStream_t stream) {
  const float* x    = (const float*)d_in[0];
  const float* bank = (const float*)d_in[1];
  const float* fc1w = (const float*)d_in[2];
  const float* fc1b = (const float*)d_in[3];
  const float* fc2w = (const float*)d_in[4];
  const float* fc2b = (const float*)d_in[5];
  float* out = (float*)d_out;

  char* ws = (char*)d_ws;
  float* gpart = (float*)(ws + 0);
  float* aout  = (float*)(ws + (1u << 20));
  unsigned short* wdyn = (unsigned short*)(ws + (2u << 20));
  unsigned short* xpt  = (unsigned short*)(ws + (2u << 20) + 18874368);

  k_xpose<<<dim3(H_, B_), 256, 0, stream>>>(x, xpt, gpart);
  k_mlp<<<dim3(B_), 128, 0, stream>>>(gpart, fc1w, fc1b, fc2w, fc2b, aout);
  k_wdyn<<<dim3(COUT), 512, 0, stream>>>(aout, bank, wdyn);
  k_conv<<<dim3(50, B_), 256, 0, stream>>>(wdyn, xpt, out);
}

// Round 5
// 237.968 us; speedup vs baseline: 1.3555x; 1.0505x over previous
//
#include <hip/hip_runtime.h>

// DynamicConv2d: GAP->MLP->softmax routing, Wdyn = sum_k a_k * bank_k,
// then per-sample 3x3 conv (pad 1) = per-sample GEMM M=256,N=3136,K=1152.
// R5: k_conv only - hoist per-lane staging offsets out of the K-loop (one
// p/56 division per thread total, was 72 with magic-mul each) and fully
// unroll t=0..17 so per-t displacements are compile-time constants.
// Aux passes byte-identical to R4.

#define CIN    128
#define COUT   256
#define KEXP   8
#define HIDDEN 32
#define B_     32
#define H_     56
#define W_     56
#define HW     3136
#define HP     58      // 1 + 56 + 1 halo rows
#define WP     58      // 1 + 56 + 1 halo cols
#define KK     1152    // 9 * 128, order (kh*3+kw)*128 + cin

typedef float  v4f  __attribute__((ext_vector_type(4)));
typedef __bf16 v8bf __attribute__((ext_vector_type(8)));

__device__ __forceinline__ unsigned short f2bf(float x) {
  unsigned int u = __float_as_uint(x);
  u += 0x7fff + ((u >> 16) & 1);          // RNE
  return (unsigned short)(u >> 16);
}

// 16B-per-lane async global->LDS. LDS dest is wave-uniform base + lane*16.
__device__ __forceinline__ void gl_lds16(const void* g, void* lds) {
  __builtin_amdgcn_global_load_lds(
      (__attribute__((address_space(1))) void*)(unsigned long long)(g),
      (__attribute__((address_space(3))) void*)(lds),
      16, 0, 0);
}

// ---------------------------------------------------------------------------
// Pass 1 (v4): x (NCHW f32) -> xp_t (padded NHWC bf16, WP=58) + GAP partials
// to gpart[h][b][c] (no atomics). Blocks also zero their own halo cells.
// ---------------------------------------------------------------------------
__global__ __launch_bounds__(256) void k_xpose(const float* __restrict__ x,
                                               unsigned short* __restrict__ xpt,
                                               float* __restrict__ gpart) {
  const int h = blockIdx.x, b = blockIdx.y, tid = threadIdx.x;
  __shared__ float tf[56 * 129];      // 28.9 KB
  __shared__ float gp[256];
  const float4* xr4 = (const float4*)x + (size_t)b * CIN * 784;  // 784=3136/4

#pragma unroll
  for (int it = 0; it < 7; ++it) {    // 1792 float4 = 128c * 14wq
    int idx = it * 256 + tid;
    int c  = idx / 14;
    int wq = idx - c * 14;
    float4 q = xr4[(size_t)c * 784 + h * 14 + wq];
    int w0 = wq * 4;
    tf[(w0 + 0) * 129 + c] = q.x;
    tf[(w0 + 1) * 129 + c] = q.y;
    tf[(w0 + 2) * 129 + c] = q.z;
    tf[(w0 + 3) * 129 + c] = q.w;
  }
  __syncthreads();

  {                                   // GAP partial: 256 threads, 28 reads each
    int c = tid & 127, half = tid >> 7;
    float s = 0.f;
#pragma unroll
    for (int w = half * 28; w < half * 28 + 28; ++w) s += tf[w * 129 + c];
    gp[tid] = s;
  }

#pragma unroll
  for (int it = 0; it < 7; ++it) {    // 1792 ushort4 stores = 56w * 32 c-quads
    int idx = it * 256 + tid;
    int w  = idx >> 5;                // [0,56)
    int c4 = (idx & 31) << 2;         // [0,128) step 4
    ushort4 o;
    o.x = f2bf(tf[w * 129 + c4 + 0]);
    o.y = f2bf(tf[w * 129 + c4 + 1]);
    o.z = f2bf(tf[w * 129 + c4 + 2]);
    o.w = f2bf(tf[w * 129 + c4 + 3]);
    *(ushort4*)(xpt + ((size_t)(b * HP + (h + 1)) * WP + (w + 1)) * CIN + c4) = o;
  }

  // halo columns 0 and 57 of this image row
  if (tid < 128) {
    size_t rb = (size_t)(b * HP + (h + 1)) * WP * CIN;
    xpt[rb + tid] = 0;
    xpt[rb + 57 * CIN + tid] = 0;
  }
  // halo rows 0 and 57 (full 58*128 ushorts each)
  if (h == 0 || h == 55) {
    int hr = (h == 0) ? 0 : 57;
    size_t rb = (size_t)(b * HP + hr) * WP * CIN;
    ushort4 z; z.x = z.y = z.z = z.w = 0;
    for (int i = tid; i < 1856; i += 256)
      *(ushort4*)(xpt + rb + i * 4) = z;
  }

  __syncthreads();
  if (tid < 128)
    gpart[((size_t)h * B_ + b) * CIN + tid] =
        (gp[tid] + gp[tid + 128]) * (1.0f / 3136.0f);
}

// ---------------------------------------------------------------------------
// Pass 2 (v2): reduce gpart -> v (in LDS), then MLP + softmax. grid=32,
// block=128.
// ---------------------------------------------------------------------------
__global__ void k_mlp(const float* __restrict__ gpart, const float* __restrict__ fc1w,
                      const float* __restrict__ fc1b, const float* __restrict__ fc2w,
                      const float* __restrict__ fc2b, float* __restrict__ aout) {
  const int b = blockIdx.x, t = threadIdx.x;
  __shared__ float vS[CIN];
  __shared__ float hid[HIDDEN];
  __shared__ float lg[KEXP];
  {
    float s = 0.f;
    for (int h = 0; h < H_; ++h) s += gpart[((size_t)h * B_ + b) * CIN + t];
    vS[t] = s;
  }
  __syncthreads();
  if (t < HIDDEN) {
    float s = fc1b[t];
    const float* wr = fc1w + t * CIN;
    for (int c = 0; c < CIN; ++c) s += vS[c] * wr[c];
    hid[t] = fmaxf(s, 0.f);
  }
  __syncthreads();
  if (t < KEXP) {
    float s = fc2b[t];
    const float* wr = fc2w + t * HIDDEN;
    for (int j = 0; j < HIDDEN; ++j) s += hid[j] * wr[j];
    lg[t] = s;
  }
  __syncthreads();
  if (t == 0) {
    float m = lg[0];
    for (int k = 1; k < KEXP; ++k) m = fmaxf(m, lg[k]);
    float e[KEXP], den = 0.f;
    for (int k = 0; k < KEXP; ++k) { e[k] = expf(lg[k] - m); den += e[k]; }
    float inv = 1.0f / den;
    for (int k = 0; k < KEXP; ++k) aout[b * KEXP + k] = e[k] * inv;
  }
}

// ---------------------------------------------------------------------------
// Pass 3 (v3): Wdyn[b][cout][kk] bf16, kk = khw*128 + cin. One block of 512
// threads per cout. Stride-9 LDS reads = 2/bank = free; coalesced stores.
// ---------------------------------------------------------------------------
__global__ __launch_bounds__(512) void k_wdyn(const float* __restrict__ aout,
                                              const float* __restrict__ bank,
                                              unsigned short* __restrict__ wdyn) {
  const int cout = blockIdx.x, tid = threadIdx.x;
  __shared__ float4 bS4[KEXP * 288];          // 36 KB
  __shared__ float aS[B_ * KEXP];             // 256 routing coeffs

  for (int idx = tid; idx < KEXP * 288; idx += 512) {
    int k = idx / 288, r = idx - k * 288;
    bS4[idx] = ((const float4*)(bank + (size_t)(k * COUT + cout) * KK))[r];
  }
  if (tid < 256) aS[tid] = aout[tid];
  __syncthreads();

  const float* bS = (const float*)bS4;
  const int lane_kk = tid & 63;
  const int sg = tid >> 6;                    // 8 groups of 4 samples
  float areg[4][KEXP];
#pragma unroll
  for (int bi = 0; bi < 4; ++bi)
#pragma unroll
    for (int k = 0; k < KEXP; ++k) areg[bi][k] = aS[(sg * 4 + bi) * KEXP + k];

  for (int it = 0; it < 18; ++it) {
    int kk  = it * 64 + lane_kk;              // [0,1152)
    int khw = kk >> 7, cin = kk & 127;
    int e   = cin * 9 + khw;
    float vv[KEXP];
#pragma unroll
    for (int k = 0; k < KEXP; ++k) vv[k] = bS[k * KK + e];
#pragma unroll
    for (int bi = 0; bi < 4; ++bi) {
      float s = 0.f;
#pragma unroll
      for (int k = 0; k < KEXP; ++k) s += areg[bi][k] * vv[k];
      wdyn[(size_t)((sg * 4 + bi) * COUT + cout) * KK + kk] = f2bf(s);
    }
  }
}

// ---------------------------------------------------------------------------
// Pass 4 (v3): conv as MFMA GEMM, exact flattened-pixel tiling.
// Staging offsets hoisted to the prologue (one p/56 per thread, total);
// t-loop fully unrolled so per-t displacements (kh*WP+kw)*CIN+cinb and t*64
// are compile-time constants -> 1 v_add per staging instruction.
// ---------------------------------------------------------------------------
__global__ __launch_bounds__(256) void k_conv(const unsigned short* __restrict__ wdyn,
                                              const unsigned short* __restrict__ xpt,
                                              float* __restrict__ out) {
  const int bx = blockIdx.x;          // 50 = 2 m-tiles * 25 pixel chunks
  const int b  = blockIdx.y;          // 32 samples
  const int bm = bx & 1, ch = bx >> 1;
  const int p0 = ch * 128;
  const int tid = threadIdx.x;
  const int wv = tid >> 6, l = tid & 63;
  const int q = l >> 4, l15 = l & 15;
  const int mq = (wv & 1) * 64, nq = (wv >> 1) * 64;

  __shared__ __align__(16) unsigned short Ash[128 * 64];  // [cout][k] swizzled
  __shared__ __align__(16) unsigned short Bsh[128 * 64];  // [pixel][k] swizzled

  const unsigned short* wb = wdyn + (size_t)(b * COUT + bm * 128) * KK;
  const unsigned short* xb = xpt + (size_t)b * HP * WP * CIN;

  // Hoisted per-lane staging offsets (ushort units), t-invariant.
  int aoff[4], boff[4];
#pragma unroll
  for (int it = 0; it < 4; ++it) {
    int g = it * 256 + tid;
    int row = g >> 3;
    int c = (g & 7) ^ (row & 7);
    aoff[it] = row * KK + c * 8;
    int p = p0 + row;
    p = p > 3135 ? 3135 : p;                  // clamp (half chunk 24)
    int ph = p / 56, pw = p - ph * 56;
    boff[it] = (ph * WP + pw) * CIN + c * 8;
  }

  v4f acc[4][4];
#pragma unroll
  for (int i = 0; i < 4; ++i)
#pragma unroll
    for (int j = 0; j < 4; ++j)
#pragma unroll
      for (int rr = 0; rr < 4; ++rr) acc[i][j][rr] = 0.f;

#pragma unroll
  for (int t = 0; t < 18; ++t) {
    const int khw = t >> 1, cinb = (t & 1) << 6;
    const int kh = khw / 3, kw = khw - 3 * kh;
    const int bd = (kh * WP + kw) * CIN + cinb;   // compile-time constant
    const int ad = t * 64;                        // compile-time constant
#pragma unroll
    for (int it = 0; it < 4; ++it)
      gl_lds16(wb + aoff[it] + ad, Ash + (it * 256 + wv * 64) * 8);
#pragma unroll
    for (int it = 0; it < 4; ++it)
      gl_lds16(xb + boff[it] + bd, Bsh + (it * 256 + wv * 64) * 8);
    __syncthreads();
#pragma unroll
    for (int ks = 0; ks < 2; ++ks) {
      v8bf af[4], bfr[4];
#pragma unroll
      for (int i = 0; i < 4; ++i) {
        int row = mq + 16 * i + l15;
        int phys = (q + 4 * ks) ^ (row & 7);
        af[i] = *(const v8bf*)(Ash + (row * 8 + phys) * 8);
      }
#pragma unroll
      for (int j = 0; j < 4; ++j) {
        int p = nq + 16 * j + l15;
        int phys = (q + 4 * ks) ^ (p & 7);
        bfr[j] = *(const v8bf*)(Bsh + (p * 8 + phys) * 8);
      }
#pragma unroll
      for (int i = 0; i < 4; ++i)
#pragma unroll
        for (int j = 0; j < 4; ++j)
          acc[i][j] = __builtin_amdgcn_mfma_f32_16x16x32_bf16(af[i], bfr[j],
                                                              acc[i][j], 0, 0, 0);
    }
    __syncthreads();
  }

  // Epilogue: D col = pixel (lane&15), D rows = cout base + 4q + rr.
#pragma unroll
  for (int j = 0; j < 4; ++j) {
    int p = p0 + nq + 16 * j + l15;
    if (p < HW) {
#pragma unroll
      for (int i = 0; i < 4; ++i) {
        int cout = bm * 128 + mq + 16 * i + 4 * q;
        float* op = out + (size_t)(b * COUT + cout) * HW + p;
#pragma unroll
        for (int rr = 0; rr < 4; ++rr) op[(size_t)rr * HW] = acc[i][j][rr];
      }
    }
  }
}

// ---------------------------------------------------------------------------
// Workspace layout (~48.5 MB, all regions fully written before read):
//   [0, 917504)            gpart f32 [56][32][128]
//   [1 MB, +1024)          a f32 [32][8]
//   [2 MB, +18874368)      Wdyn bf16 [b][cout][1152]
//   [2MB+18874368, +27553792)  xp_t bf16 [b][58][58][128]
// ---------------------------------------------------------------------------
extern "C" void kernel_launch(void* const* d_in, const int* in_sizes, int n_in,
                              void* d_out, int out_size, void* d_ws, size_t ws_size,
                              hipStream_t stream) {
  const float* x    = (const float*)d_in[0];
  const float* bank = (const float*)d_in[1];
  const float* fc1w = (const float*)d_in[2];
  const float* fc1b = (const float*)d_in[3];
  const float* fc2w = (const float*)d_in[4];
  const float* fc2b = (const float*)d_in[5];
  float* out = (float*)d_out;

  char* ws = (char*)d_ws;
  float* gpart = (float*)(ws + 0);
  float* aout  = (float*)(ws + (1u << 20));
  unsigned short* wdyn = (unsigned short*)(ws + (2u << 20));
  unsigned short* xpt  = (unsigned short*)(ws + (2u << 20) + 18874368);

  k_xpose<<<dim3(H_, B_), 256, 0, stream>>>(x, xpt, gpart);
  k_mlp<<<dim3(B_), 128, 0, stream>>>(gpart, fc1w, fc1b, fc2w, fc2b, aout);
  k_wdyn<<<dim3(COUT), 512, 0, stream>>>(aout, bank, wdyn);
  k_conv<<<dim3(50, B_), 256, 0, stream>>>(wdyn, xpt, out);
}